// Round 1
// baseline (339.842 us; speedup 1.0000x reference)
//
#include <hip/hip_runtime.h>
#include <hip/hip_fp16.h>
#include <hip/hip_cooperative_groups.h>
#include <math.h>

namespace cg = cooperative_groups;

// ---------------------------------------------------------------------------
// VariationalGCNEncoder: N=50000, E=800000, 128 -> 64 -> {32,32}
// R12: (a) CSR build (hist+bscan+scatterA+phaseB) fused into ONE cooperative
//      kernel with 2 grid.sync()s. Edge records + per-block bucket ranks are
//      computed once and carried in REGISTERS across the sync (kills the
//      scatterA re-read of src/dst and the duplicate LDS rank pass). The
//      1-block bscan kernel is gone: every block scans bcount[256] locally.
//      Phase B stages its ~16KB rec slice in LDS (single global pass).
//      (b) Gathers go quarter-wave: lane loads uint2 (8B), 16 lanes = one
//      128B row, 4 edges per load instr (half the VMEM/shfl instructions).
// Pipeline (5 dispatches):
//   memset(bcount|bcursor) -> k_build (coop)
//   gemm: hp = dinv[row] * (bf16(x) @ bf16(W1))                     bf16
//   gather1: hm = dinv * relu(dinv*(sum hp[src] + hp[n]) + b1)      bf16
//   gather2: out = dinv*(sum hm[src] + hm[n]) @ [Wmu|Wls] + bias    f32
// ---------------------------------------------------------------------------

typedef unsigned int uint;
typedef unsigned short ushort;
typedef __attribute__((ext_vector_type(8))) short short8;   // 8 bf16 = 4 VGPR
typedef __attribute__((ext_vector_type(4))) float f32x4;    // MFMA acc / quad

__device__ __forceinline__ ushort f2bf(float x) {          // f32 -> bf16 RNE
    uint u = __float_as_uint(x);
    u += 0x7fffu + ((u >> 16) & 1u);
    return (ushort)(u >> 16);
}
__device__ __forceinline__ float bf2f(ushort h) {
    return __uint_as_float((uint)h << 16);
}

// ---- fused CSR build: one cooperative kernel, 3 phases --------------------
// rec = src(16) | dstlow(8)<<16 | bucket(8)<<24 ; bucket = dst>>8
__global__ __launch_bounds__(256, 2) void k_build(
        const int* __restrict__ src, const int* __restrict__ dst,
        int* __restrict__ bcount, int* __restrict__ bcursor,
        uint* __restrict__ recs, int* __restrict__ row_ptr,
        float* __restrict__ dinv, ushort* __restrict__ edges,
        int N, int E, int NBUCK) {
    __shared__ int h[256];
    __shared__ int p[256];
    __shared__ uint rstage[8192];          // 32KB phase-B rec staging
    __shared__ int s_base, s_cnt;
    const int tid = threadIdx.x;
    const int bx  = blockIdx.x;
    cg::grid_group grid = cg::this_grid();

    // -- phase 1: coarse histogram + per-block ranks; records stay in regs --
    h[tid] = 0;
    __syncthreads();
    uint rec[8]; int rk[8];
    const int base = bx * 2048;
    #pragma unroll
    for (int k = 0; k < 8; ++k) {
        int i = base + k * 256 + tid;
        rk[k] = 0;
        if (i < E) {
            int s = __builtin_nontemporal_load(src + i);
            int d = __builtin_nontemporal_load(dst + i);
            int b = d >> 8;
            rec[k] = (uint)s | ((uint)(d & 255) << 16) | ((uint)b << 24);
            rk[k] = atomicAdd(&h[b], 1);
        }
    }
    __syncthreads();
    const int hv = h[tid];                 // this block's count for bucket tid
    if (hv) atomicAdd(&bcount[tid], hv);
    grid.sync();

    // -- phase 2: local scan of bcount -> bases; claim cursor; scatter recs --
    int v = bcount[tid];
    p[tid] = v;
    __syncthreads();
    #pragma unroll
    for (int off = 1; off < 256; off <<= 1) {
        int x = (tid >= off) ? p[tid - off] : 0;
        __syncthreads();
        p[tid] += x;
        __syncthreads();
    }
    const int myExcl = p[tid] - v;         // global base of bucket `tid`
    const int myCnt  = v;                  // total count of bucket `tid`
    int rb_ = myExcl + (hv ? atomicAdd(&bcursor[tid], hv) : 0);
    __syncthreads();
    p[tid] = rb_;                          // reuse p as this block's run base
    __syncthreads();
    #pragma unroll
    for (int k = 0; k < 8; ++k) {
        int i = base + k * 256 + tid;
        if (i < E) recs[p[rec[k] >> 24] + rk[k]] = rec[k];
    }
    __threadfence();
    grid.sync();
    if (bx >= NBUCK) return;

    // -- phase B: one block per bucket; row_ptr+dinv; u16 edge scatter ------
    if (tid == bx) { s_base = myExcl; s_cnt = myCnt; }   // carried in regs
    __syncthreads();
    const int bs  = s_base;
    const int cnt = s_cnt;
    h[tid] = 0;
    __syncthreads();
    const bool stg = (cnt <= 8192);
    for (int i = tid; i < cnt; i += 256) {
        uint r = recs[bs + i];
        if (stg) rstage[i] = r;
        atomicAdd(&h[(r >> 16) & 255], 1);
    }
    __syncthreads();
    v = h[tid];
    p[tid] = v;
    __syncthreads();
    #pragma unroll
    for (int off = 1; off < 256; off <<= 1) {
        int x = (tid >= off) ? p[tid - off] : 0;
        __syncthreads();
        p[tid] += x;
        __syncthreads();
    }
    const int excl = p[tid] - v;
    const int node = bx * 256 + tid;
    if (node < N) {
        row_ptr[node] = bs + excl;
        dinv[node] = rsqrtf((float)(v + 1));
    }
    if (bx == NBUCK - 1 && tid == 0) row_ptr[N] = E;
    h[tid] = excl;                         // reuse as local cursor
    __syncthreads();
    for (int i = tid; i < cnt; i += 256) {
        uint r = stg ? rstage[i] : recs[bs + i];
        int pos = atomicAdd(&h[(r >> 16) & 255], 1);
        edges[bs + pos] = (ushort)(r & 0xffffu);
    }
}

// ---- MFMA gemm with dinv-prescale epilogue: hp = dinv[row]*(x@W1) ----
__global__ __launch_bounds__(256, 4) void k_gemm(
        const float* __restrict__ x, const float* __restrict__ W1,
        const float* __restrict__ dinv, ushort* __restrict__ hp, int N) {
    const int tid = threadIdx.x;
    const int w = tid >> 6, l = tid & 63;
    const int m = l & 15, q = l >> 4;              // q = quad (0..3)
    const int row0 = blockIdx.x * 64 + w * 16;
    const size_t arow = (size_t)min(row0 + m, N - 1);   // clamp; store guarded
    f32x4 acc0 = {0.f, 0.f, 0.f, 0.f}, acc1 = acc0, acc2 = acc0, acc3 = acc0;
    #pragma unroll
    for (int kc = 0; kc < 4; ++kc) {
        const int kofs = kc * 32 + q * 8;
        const float4* xr = (const float4*)(x + arow * 128 + kofs);
        float4 xa = xr[0], xb = xr[1];
        short8 a;
        a[0] = (short)f2bf(xa.x); a[1] = (short)f2bf(xa.y);
        a[2] = (short)f2bf(xa.z); a[3] = (short)f2bf(xa.w);
        a[4] = (short)f2bf(xb.x); a[5] = (short)f2bf(xb.y);
        a[6] = (short)f2bf(xb.z); a[7] = (short)f2bf(xb.w);
        short8 b0, b1, b2, b3;                     // W1 L1-hot (32 KB)
        #pragma unroll
        for (int i = 0; i < 8; ++i) {
            const float* wk = W1 + (size_t)(kofs + i) * 64 + m;
            b0[i] = (short)f2bf(wk[0]);
            b1[i] = (short)f2bf(wk[16]);
            b2[i] = (short)f2bf(wk[32]);
            b3[i] = (short)f2bf(wk[48]);
        }
        acc0 = __builtin_amdgcn_mfma_f32_16x16x32_bf16(a, b0, acc0, 0, 0, 0);
        acc1 = __builtin_amdgcn_mfma_f32_16x16x32_bf16(a, b1, acc1, 0, 0, 0);
        acc2 = __builtin_amdgcn_mfma_f32_16x16x32_bf16(a, b2, acc2, 0, 0, 0);
        acc3 = __builtin_amdgcn_mfma_f32_16x16x32_bf16(a, b3, acc3, 0, 0, 0);
    }
    #pragma unroll
    for (int r = 0; r < 4; ++r) {                  // D: row=q*4+r, col=g*16+m
        int row = row0 + q * 4 + r;
        if (row >= N) continue;
        float dv = dinv[row];
        ushort* hr = hp + (size_t)row * 64 + m;
        hr[0]  = f2bf(acc0[r] * dv);
        hr[16] = f2bf(acc1[r] * dv);
        hr[32] = f2bf(acc2[r] * dv);
        hr[48] = f2bf(acc3[r] * dv);
    }
}

// Norm-free gather over 64-feature rows. Quarter-wave per edge: ql = lane&15
// (uint2 = 4 feats), q = lane>>4 (edge mod 4). 4 edges per load instr,
// 8-step unroll = 32 edges in flight. Pure f32x4 adds. Butterfly over quads.
__device__ __forceinline__ f32x4 gather_rows4(
        const uint* __restrict__ hp, const ushort* __restrict__ edges,
        int beg, int end, int E, int lane, int ql, int q) {
    f32x4 acc = {0.f, 0.f, 0.f, 0.f};
    for (int base = beg; base < end; base += 64) {
        int cnt = end - base; if (cnt > 64) cnt = 64;
        int mrec = (int)edges[min(base + lane, E - 1)];   // coalesced 2B/lane
        int steps = (cnt + 3) >> 2;
        for (int t = 0; t < steps; t += 8) {
            if (4 * t + 32 <= cnt) {       // edges 4t..4t+31 all valid
                #pragma unroll
                for (int i = 0; i < 8; ++i) {
                    int r = __shfl(mrec, 4 * (t + i) + q);
                    uint2 v = *(const uint2*)(hp + (size_t)r * 32 + 2 * ql);
                    f32x4 vf;
                    vf.x = __uint_as_float(v.x << 16);
                    vf.y = __uint_as_float(v.x & 0xffff0000u);
                    vf.z = __uint_as_float(v.y << 16);
                    vf.w = __uint_as_float(v.y & 0xffff0000u);
                    acc = acc + vf;
                }
            } else {
                #pragma unroll
                for (int i = 0; i < 8; ++i) {
                    int e = 4 * (t + i) + q;
                    int r = __shfl(mrec, min(e, cnt - 1));
                    uint2 v = *(const uint2*)(hp + (size_t)r * 32 + 2 * ql);
                    if (e >= cnt) { v.x = 0u; v.y = 0u; }
                    f32x4 vf;
                    vf.x = __uint_as_float(v.x << 16);
                    vf.y = __uint_as_float(v.x & 0xffff0000u);
                    vf.z = __uint_as_float(v.y << 16);
                    vf.w = __uint_as_float(v.y & 0xffff0000u);
                    acc = acc + vf;
                }
            }
        }
    }
    acc.x += __shfl_xor(acc.x, 16); acc.y += __shfl_xor(acc.y, 16);
    acc.z += __shfl_xor(acc.z, 16); acc.w += __shfl_xor(acc.w, 16);
    acc.x += __shfl_xor(acc.x, 32); acc.y += __shfl_xor(acc.y, 32);
    acc.z += __shfl_xor(acc.z, 32); acc.w += __shfl_xor(acc.w, 32);
    return acc;
}

// hm[n] = dinv * relu( dinv * (sum hp[src] + hp[n]) + b1 )   (bf16x2)
__global__ __launch_bounds__(256, 6) void k_gather1(
        const uint* __restrict__ hp, const int* __restrict__ row_ptr,
        const ushort* __restrict__ edges, const float* __restrict__ dinv,
        const float* __restrict__ b1, uint* __restrict__ ho, int N, int E) {
    const int lane = threadIdx.x & 63;
    const int ql = lane & 15, q = lane >> 4;
    const int n = blockIdx.x * 4 + (threadIdx.x >> 6);
    if (n >= N) return;
    const int beg = row_ptr[n], end = row_ptr[n + 1];
    f32x4 acc = gather_rows4(hp, edges, beg, end, E, lane, ql, q);
    if (q == 0) {
        const float dv = dinv[n];
        uint2 sv = *(const uint2*)(hp + (size_t)n * 32 + 2 * ql);  // self
        float4 b = ((const float4*)b1)[ql];
        float s0 = acc.x + bf2f((ushort)sv.x);
        float s1 = acc.y + bf2f((ushort)(sv.x >> 16));
        float s2 = acc.z + bf2f((ushort)sv.y);
        float s3 = acc.w + bf2f((ushort)(sv.y >> 16));
        float h0 = fmaxf(fmaf(dv, s0, b.x), 0.f) * dv;  // relu then pre-scale
        float h1 = fmaxf(fmaf(dv, s1, b.y), 0.f) * dv;
        float h2 = fmaxf(fmaf(dv, s2, b.z), 0.f) * dv;
        float h3 = fmaxf(fmaf(dv, s3, b.w), 0.f) * dv;
        uint2 o;
        o.x = (uint)f2bf(h0) | ((uint)f2bf(h1) << 16);
        o.y = (uint)f2bf(h2) | ((uint)f2bf(h3) << 16);
        *(uint2*)(ho + (size_t)n * 32 + 2 * ql) = o;
    }
}

// g = dinv*(sum hm[src] + hm[n]);  out[n] = g @ [Wmu|Wls] + bias
__global__ __launch_bounds__(256, 6) void k_gather2(
        const uint* __restrict__ hp, const int* __restrict__ row_ptr,
        const ushort* __restrict__ edges, const float* __restrict__ dinv,
        const float* __restrict__ Wmu, const float* __restrict__ Wls,
        const float* __restrict__ bmu, const float* __restrict__ bls,
        float* __restrict__ out, int N, int E) {
    __shared__ __align__(16) float hs[4][64];   // per-wave g row (1 KB)
    const int lane = threadIdx.x & 63;
    const int ql = lane & 15, q = lane >> 4;
    const int w = threadIdx.x >> 6;
    const int n = blockIdx.x * 4 + w;
    if (n >= N) return;
    const int beg = row_ptr[n], end = row_ptr[n + 1];
    f32x4 acc = gather_rows4(hp, edges, beg, end, E, lane, ql, q);
    if (q == 0) {
        const float dv = dinv[n];
        uint2 sv = *(const uint2*)(hp + (size_t)n * 32 + 2 * ql);
        float4 g;
        g.x = dv * (acc.x + bf2f((ushort)sv.x));
        g.y = dv * (acc.y + bf2f((ushort)(sv.x >> 16)));
        g.z = dv * (acc.z + bf2f((ushort)sv.y));
        g.w = dv * (acc.w + bf2f((ushort)(sv.y >> 16)));
        *(float4*)&hs[w][4 * ql] = g;
    }
    // epilogue: out_row = g @ [Wmu|Wls] + bias ; W from global (L1-hot)
    const float* Wsel = (lane < 32) ? (Wmu + lane) : (Wls + (lane - 32));
    const float bias  = (lane < 32) ? bmu[lane] : bls[lane - 32];
    float c0 = 0.f, c1 = 0.f, c2 = 0.f, c3 = 0.f;
    #pragma unroll 4
    for (int k = 0; k < 64; k += 4) {
        c0 = fmaf(hs[w][k + 0], Wsel[(k + 0) * 32], c0);
        c1 = fmaf(hs[w][k + 1], Wsel[(k + 1) * 32], c1);
        c2 = fmaf(hs[w][k + 2], Wsel[(k + 2) * 32], c2);
        c3 = fmaf(hs[w][k + 3], Wsel[(k + 3) * 32], c3);
    }
    float t = (c0 + c1) + (c2 + c3) + bias;
    if (lane < 32) out[(size_t)n * 32 + lane] = t;
    else           out[(size_t)N * 32 + (size_t)n * 32 + (lane - 32)] = t;
}

extern "C" void kernel_launch(void* const* d_in, const int* in_sizes, int n_in,
                              void* d_out, int out_size, void* d_ws, size_t ws_size,
                              hipStream_t stream) {
    const float* x   = (const float*)d_in[0];
    const int*   ei  = (const int*)d_in[1];
    const float* W1  = (const float*)d_in[2];
    const float* b1  = (const float*)d_in[3];
    const float* Wmu = (const float*)d_in[4];
    const float* bmu = (const float*)d_in[5];
    const float* Wls = (const float*)d_in[6];
    const float* bls = (const float*)d_in[7];
    float* out = (float*)d_out;

    const int N = in_sizes[0] / 128;          // 50000  (< 65536: u16 src pack)
    const int E = in_sizes[1] / 2;            // 800000
    const int* src = ei;
    const int* dst = ei + E;
    const int HB    = (E + 2047) / 2048;      // build blocks (391)
    const int NBUCK = (N + 255) / 256;        // coarse buckets (196)
    const int GB    = (N + 63) / 64;          // gemm row-tile blocks
    const int NG    = (N + 3) / 4;            // gather blocks

    char* w = (char*)d_ws;
    auto carve = [&](size_t bytes) { char* p = w; w += (bytes + 1023) & ~(size_t)1023; return p; };
    int*    bcount  = (int*)   carve(512 * 4);             // [bcount|bcursor]
    int*    bcursor = bcount + 256;
    uint*   recs    = (uint*)  carve((size_t)E * 4);       // level-A records
    int*    row_ptr = (int*)   carve((size_t)(N + 1) * 4);
    float*  dinv    = (float*) carve((size_t)N * 4);
    ushort* edges   = (ushort*)carve((size_t)E * 2);       // u16 src records
    ushort* h_pre   = (ushort*)carve((size_t)N * 64 * 2);  // bf16 (pre-scaled)
    ushort* h_mid   = (ushort*)carve((size_t)N * 64 * 2);  // bf16 (pre-scaled)

    hipMemsetAsync(bcount, 0, 512 * 4, stream);

    int N_ = N, E_ = E, NBUCK_ = NBUCK;
    void* kargs[] = {(void*)&src, (void*)&dst, (void*)&bcount, (void*)&bcursor,
                     (void*)&recs, (void*)&row_ptr, (void*)&dinv, (void*)&edges,
                     (void*)&N_, (void*)&E_, (void*)&NBUCK_};
    hipLaunchCooperativeKernel(k_build, dim3(HB), dim3(256), kargs, 0, stream);

    k_gemm    <<<GB, 256, 0, stream>>>(x, W1, dinv, h_pre, N);
    k_gather1 <<<NG, 256, 0, stream>>>((const uint*)h_pre, row_ptr, edges, dinv,
                                       b1, (uint*)h_mid, N, E);
    k_gather2 <<<NG, 256, 0, stream>>>((const uint*)h_mid, row_ptr, edges, dinv,
                                       Wmu, Wls, bmu, bls, out, N, E);
}

// Round 2
// 188.811 us; speedup vs baseline: 1.7999x; 1.7999x over previous
//
#include <hip/hip_runtime.h>
#include <hip/hip_fp16.h>
#include <math.h>

// ---------------------------------------------------------------------------
// VariationalGCNEncoder: N=50000, E=800000, 128 -> 64 -> {32,32}
// R13: revert R12's cooperative fusion (grid.sync() costs ~65us each on this
//      stack: k_build ran 160us at 0.6% VALU -- pure barrier idle).
//      (a) Build is back to split kernels, but k_bscan is GONE: scatterA and
//          phaseB each re-scan bcount[256] locally in LDS (1KB L2-hot read).
//      (b) Gathers redesigned: 16-lane GROUP per node (4 nodes/wave).
//          Lane owns 4 features (uint2); no cross-node butterfly reduce;
//          epilogue uses all 64 lanes; no clamped-duplicate row reads
//          (old quarter-wave forced 8-step unroll = ~4KB read per 2KB useful).
//          Gather L2 traffic ~halves; MLP kept at 8 via explicit 8-batches.
// Pipeline (6 dispatches):
//   memset(bcount|bcursor) -> hist -> scatterA -> phaseB
//   gemm: hp = dinv[row] * (bf16(x) @ bf16(W1))                     bf16
//   gather1: hm = dinv * relu(dinv*(sum hp[src] + hp[n]) + b1)      bf16
//   gather2: out = dinv*(sum hm[src] + hm[n]) @ [Wmu|Wls] + bias    f32
// ---------------------------------------------------------------------------

typedef unsigned int uint;
typedef unsigned short ushort;
typedef __attribute__((ext_vector_type(8))) short short8;   // 8 bf16 = 4 VGPR
typedef __attribute__((ext_vector_type(4))) float f32x4;    // MFMA acc / quad

__device__ __forceinline__ ushort f2bf(float x) {          // f32 -> bf16 RNE
    uint u = __float_as_uint(x);
    u += 0x7fffu + ((u >> 16) & 1u);
    return (ushort)(u >> 16);
}
__device__ __forceinline__ float bf2f(ushort h) {
    return __uint_as_float((uint)h << 16);
}

// ---- CSR build, level A: coarse histogram (2048 edges/block) ----
__global__ __launch_bounds__(256) void k_hist(
        const int* __restrict__ dst, int* __restrict__ bcount, int E) {
    __shared__ int h[256];
    const int tid = threadIdx.x;
    h[tid] = 0;
    __syncthreads();
    const int base = blockIdx.x * 2048;
    #pragma unroll
    for (int k = 0; k < 8; ++k) {
        int i = base + k * 256 + tid;
        if (i < E) {
            int d = __builtin_nontemporal_load(dst + i);
            atomicAdd(&h[d >> 8], 1);
        }
    }
    __syncthreads();
    if (h[tid]) atomicAdd(&bcount[tid], h[tid]);
}

// ---- level A scatter: rec = src(16) | dstlow(8)<<16 | bucket(8)<<24 ----
// Local LDS scan of bcount replaces the old 1-block bscan kernel.
// Per-block LDS rank + one cursor atomic per (block,bucket) -> contiguous runs.
__global__ __launch_bounds__(256) void k_scatterA(
        const int* __restrict__ src, const int* __restrict__ dst,
        const int* __restrict__ bcount, int* __restrict__ bcursor,
        uint* __restrict__ recs, int E) {
    __shared__ int h[256];
    __shared__ int p[256];
    __shared__ int rb[256];
    const int tid = threadIdx.x;
    h[tid] = 0;
    __syncthreads();
    const int base = blockIdx.x * 2048;
    uint rec[8]; int rk[8];
    #pragma unroll
    for (int k = 0; k < 8; ++k) {
        int i = base + k * 256 + tid;
        if (i < E) {
            int s = __builtin_nontemporal_load(src + i);
            int d = __builtin_nontemporal_load(dst + i);
            int b = d >> 8;
            rec[k] = (uint)s | ((uint)(d & 255) << 16) | ((uint)b << 24);
            rk[k] = atomicAdd(&h[b], 1);
        }
    }
    // local scan of bcount -> bucket bases (counts are final after k_hist)
    int v = bcount[tid];
    p[tid] = v;
    __syncthreads();                        // also fences the h atomics above
    #pragma unroll
    for (int off = 1; off < 256; off <<= 1) {
        int x = (tid >= off) ? p[tid - off] : 0;
        __syncthreads();
        p[tid] += x;
        __syncthreads();
    }
    const int excl = p[tid] - v;            // global base of bucket `tid`
    const int hv = h[tid];
    rb[tid] = excl + (hv ? atomicAdd(&bcursor[tid], hv) : 0);
    __syncthreads();
    #pragma unroll
    for (int k = 0; k < 8; ++k) {
        int i = base + k * 256 + tid;
        if (i < E) recs[rb[rec[k] >> 24] + rk[k]] = rec[k];
    }
}

// ---- level B: one block per bucket. Local scan of bcount -> base/cnt.
// row_ptr+dinv coalesced; recs staged in LDS; u16 edge scatter block-local.
__global__ __launch_bounds__(256, 4) void k_phaseB(
        const uint* __restrict__ recs, const int* __restrict__ bcount,
        int* __restrict__ row_ptr, float* __restrict__ dinv,
        ushort* __restrict__ edges, int N, int E, int NBUCK) {
    __shared__ int h[256];
    __shared__ int p[256];
    __shared__ uint rstage[8192];          // 32KB rec staging
    const int tid = threadIdx.x;
    const int bx  = blockIdx.x;
    int v = bcount[tid];
    p[tid] = v;
    h[tid] = 0;
    __syncthreads();
    #pragma unroll
    for (int off = 1; off < 256; off <<= 1) {
        int x = (tid >= off) ? p[tid - off] : 0;
        __syncthreads();
        p[tid] += x;
        __syncthreads();
    }
    const int cnt = bcount[bx];
    const int bs  = p[bx] - cnt;           // excl prefix at bx
    const bool stg = (cnt <= 8192);
    for (int i = tid; i < cnt; i += 256) {
        uint r = recs[bs + i];
        if (stg) rstage[i] = r;
        atomicAdd(&h[(r >> 16) & 255], 1);
    }
    __syncthreads();
    v = h[tid];
    p[tid] = v;
    __syncthreads();
    #pragma unroll
    for (int off = 1; off < 256; off <<= 1) {
        int x = (tid >= off) ? p[tid - off] : 0;
        __syncthreads();
        p[tid] += x;
        __syncthreads();
    }
    const int excl = p[tid] - v;
    const int node = bx * 256 + tid;
    if (node < N) {
        row_ptr[node] = bs + excl;
        dinv[node] = rsqrtf((float)(v + 1));
    }
    if (bx == NBUCK - 1 && tid == 0) row_ptr[N] = E;
    h[tid] = excl;                         // reuse as local cursor
    __syncthreads();
    for (int i = tid; i < cnt; i += 256) {
        uint r = stg ? rstage[i] : recs[bs + i];
        int pos = atomicAdd(&h[(r >> 16) & 255], 1);
        edges[bs + pos] = (ushort)(r & 0xffffu);
    }
}

// ---- MFMA gemm with dinv-prescale epilogue: hp = dinv[row]*(x@W1) ----
__global__ __launch_bounds__(256, 4) void k_gemm(
        const float* __restrict__ x, const float* __restrict__ W1,
        const float* __restrict__ dinv, ushort* __restrict__ hp, int N) {
    const int tid = threadIdx.x;
    const int w = tid >> 6, l = tid & 63;
    const int m = l & 15, q = l >> 4;              // q = quad (0..3)
    const int row0 = blockIdx.x * 64 + w * 16;
    const size_t arow = (size_t)min(row0 + m, N - 1);   // clamp; store guarded
    f32x4 acc0 = {0.f, 0.f, 0.f, 0.f}, acc1 = acc0, acc2 = acc0, acc3 = acc0;
    #pragma unroll
    for (int kc = 0; kc < 4; ++kc) {
        const int kofs = kc * 32 + q * 8;
        const float4* xr = (const float4*)(x + arow * 128 + kofs);
        float4 xa = xr[0], xb = xr[1];
        short8 a;
        a[0] = (short)f2bf(xa.x); a[1] = (short)f2bf(xa.y);
        a[2] = (short)f2bf(xa.z); a[3] = (short)f2bf(xa.w);
        a[4] = (short)f2bf(xb.x); a[5] = (short)f2bf(xb.y);
        a[6] = (short)f2bf(xb.z); a[7] = (short)f2bf(xb.w);
        short8 b0, b1, b2, b3;                     // W1 L1-hot (32 KB)
        #pragma unroll
        for (int i = 0; i < 8; ++i) {
            const float* wk = W1 + (size_t)(kofs + i) * 64 + m;
            b0[i] = (short)f2bf(wk[0]);
            b1[i] = (short)f2bf(wk[16]);
            b2[i] = (short)f2bf(wk[32]);
            b3[i] = (short)f2bf(wk[48]);
        }
        acc0 = __builtin_amdgcn_mfma_f32_16x16x32_bf16(a, b0, acc0, 0, 0, 0);
        acc1 = __builtin_amdgcn_mfma_f32_16x16x32_bf16(a, b1, acc1, 0, 0, 0);
        acc2 = __builtin_amdgcn_mfma_f32_16x16x32_bf16(a, b2, acc2, 0, 0, 0);
        acc3 = __builtin_amdgcn_mfma_f32_16x16x32_bf16(a, b3, acc3, 0, 0, 0);
    }
    #pragma unroll
    for (int r = 0; r < 4; ++r) {                  // D: row=q*4+r, col=g*16+m
        int row = row0 + q * 4 + r;
        if (row >= N) continue;
        float dv = dinv[row];
        ushort* hr = hp + (size_t)row * 64 + m;
        hr[0]  = f2bf(acc0[r] * dv);
        hr[16] = f2bf(acc1[r] * dv);
        hr[32] = f2bf(acc2[r] * dv);
        hr[48] = f2bf(acc3[r] * dv);
    }
}

// ---- group gather: 16-lane group owns one node; lane owns 4 features ----
// Per 16-edge chunk: one coalesced edges load, then per-edge the whole group
// reads that src row (16 lanes x uint2 = 128B). Two 8-batches keep MLP=8.
// No cross-lane reduction needed: features are disjoint across lanes.
__device__ __forceinline__ f32x4 gather_grp(
        const uint* __restrict__ hp, const ushort* __restrict__ edges,
        int beg, int end, int E, int ql) {
    f32x4 acc = {0.f, 0.f, 0.f, 0.f};
    const int len = end - beg;
    int base = beg;
    for (int c = len >> 4; c > 0; --c, base += 16) {   // full 16-edge chunks
        int mrec = (int)edges[base + ql];
        #pragma unroll
        for (int half = 0; half < 2; ++half) {
            #pragma unroll
            for (int i = 0; i < 8; ++i) {
                int r = __shfl(mrec, half * 8 + i, 16);
                uint2 v = *(const uint2*)(hp + (size_t)r * 32 + 2 * ql);
                f32x4 vf;
                vf.x = __uint_as_float(v.x << 16);
                vf.y = __uint_as_float(v.x & 0xffff0000u);
                vf.z = __uint_as_float(v.y << 16);
                vf.w = __uint_as_float(v.y & 0xffff0000u);
                acc = acc + vf;
            }
        }
    }
    const int rem = len & 15;
    if (rem) {
        int mrec = (int)edges[min(base + ql, E - 1)];
        for (int i = 0; i < rem; i += 4) {
            #pragma unroll
            for (int j = 0; j < 4; ++j) {
                int e = i + j;
                int r = __shfl(mrec, min(e, rem - 1), 16);
                uint2 v = *(const uint2*)(hp + (size_t)r * 32 + 2 * ql);
                if (e >= rem) { v.x = 0u; v.y = 0u; }
                f32x4 vf;
                vf.x = __uint_as_float(v.x << 16);
                vf.y = __uint_as_float(v.x & 0xffff0000u);
                vf.z = __uint_as_float(v.y << 16);
                vf.w = __uint_as_float(v.y & 0xffff0000u);
                acc = acc + vf;
            }
        }
    }
    return acc;
}

// hm[n] = dinv * relu( dinv * (sum hp[src] + hp[n]) + b1 )   (bf16x2)
__global__ __launch_bounds__(256, 8) void k_gather1(
        const uint* __restrict__ hp, const int* __restrict__ row_ptr,
        const ushort* __restrict__ edges, const float* __restrict__ dinv,
        const float* __restrict__ b1, uint* __restrict__ ho, int N, int E) {
    const int lane = threadIdx.x & 63;
    const int ql = lane & 15;
    const int n = blockIdx.x * 16 + ((threadIdx.x >> 6) << 2) + (lane >> 4);
    const int nc = min(n, N - 1);
    const int beg = row_ptr[nc], end = row_ptr[nc + 1];
    f32x4 acc = gather_grp(hp, edges, beg, end, E, ql);
    const float dv = dinv[nc];
    const uint2 sv = *(const uint2*)(hp + (size_t)nc * 32 + 2 * ql);  // self
    const float4 b = ((const float4*)b1)[ql];
    float s0 = acc.x + bf2f((ushort)sv.x);
    float s1 = acc.y + bf2f((ushort)(sv.x >> 16));
    float s2 = acc.z + bf2f((ushort)sv.y);
    float s3 = acc.w + bf2f((ushort)(sv.y >> 16));
    float h0 = fmaxf(fmaf(dv, s0, b.x), 0.f) * dv;  // relu then pre-scale
    float h1 = fmaxf(fmaf(dv, s1, b.y), 0.f) * dv;
    float h2 = fmaxf(fmaf(dv, s2, b.z), 0.f) * dv;
    float h3 = fmaxf(fmaf(dv, s3, b.w), 0.f) * dv;
    if (n < N) {
        uint2 o;
        o.x = (uint)f2bf(h0) | ((uint)f2bf(h1) << 16);
        o.y = (uint)f2bf(h2) | ((uint)f2bf(h3) << 16);
        *(uint2*)(ho + (size_t)n * 32 + 2 * ql) = o;
    }
}

// g = dinv*(sum hm[src] + hm[n]);  out[n] = g @ [Wmu|Wls] + bias
__global__ __launch_bounds__(256, 8) void k_gather2(
        const uint* __restrict__ hp, const int* __restrict__ row_ptr,
        const ushort* __restrict__ edges, const float* __restrict__ dinv,
        const float* __restrict__ Wmu, const float* __restrict__ Wls,
        const float* __restrict__ bmu, const float* __restrict__ bls,
        float* __restrict__ out, int N, int E) {
    __shared__ __align__(16) float hs[4][4][64];   // [wave][group-node][feat]
    const int lane = threadIdx.x & 63;
    const int ql = lane & 15, grp = lane >> 4;
    const int w = threadIdx.x >> 6;
    const int n = blockIdx.x * 16 + (w << 2) + grp;
    const int nc = min(n, N - 1);
    const int beg = row_ptr[nc], end = row_ptr[nc + 1];
    f32x4 acc = gather_grp(hp, edges, beg, end, E, ql);
    const float dv = dinv[nc];
    const uint2 sv = *(const uint2*)(hp + (size_t)nc * 32 + 2 * ql);
    float4 g;
    g.x = dv * (acc.x + bf2f((ushort)sv.x));
    g.y = dv * (acc.y + bf2f((ushort)(sv.x >> 16)));
    g.z = dv * (acc.z + bf2f((ushort)sv.y));
    g.w = dv * (acc.w + bf2f((ushort)(sv.y >> 16)));
    *(float4*)&hs[w][grp][4 * ql] = g;
    // epilogue: out_row = g @ [Wmu|Wls] + bias for the wave's 4 nodes.
    // W column load hoisted across nodes; hs reads are LDS broadcasts.
    const float* Wsel = (lane < 32) ? (Wmu + lane) : (Wls + (lane - 32));
    const float bias  = (lane < 32) ? bmu[lane] : bls[lane - 32];
    float c0 = 0.f, c1 = 0.f, c2 = 0.f, c3 = 0.f;
    #pragma unroll 4
    for (int k = 0; k < 64; ++k) {
        float wv = Wsel[k * 32];
        c0 = fmaf(hs[w][0][k], wv, c0);
        c1 = fmaf(hs[w][1][k], wv, c1);
        c2 = fmaf(hs[w][2][k], wv, c2);
        c3 = fmaf(hs[w][3][k], wv, c3);
    }
    const int n0 = blockIdx.x * 16 + (w << 2);
    float cs[4] = {c0, c1, c2, c3};
    #pragma unroll
    for (int gg = 0; gg < 4; ++gg) {
        int nn = n0 + gg;
        if (nn >= N) break;
        float t = cs[gg] + bias;
        if (lane < 32) out[(size_t)nn * 32 + lane] = t;
        else           out[(size_t)N * 32 + (size_t)nn * 32 + (lane - 32)] = t;
    }
}

extern "C" void kernel_launch(void* const* d_in, const int* in_sizes, int n_in,
                              void* d_out, int out_size, void* d_ws, size_t ws_size,
                              hipStream_t stream) {
    const float* x   = (const float*)d_in[0];
    const int*   ei  = (const int*)d_in[1];
    const float* W1  = (const float*)d_in[2];
    const float* b1  = (const float*)d_in[3];
    const float* Wmu = (const float*)d_in[4];
    const float* bmu = (const float*)d_in[5];
    const float* Wls = (const float*)d_in[6];
    const float* bls = (const float*)d_in[7];
    float* out = (float*)d_out;

    const int N = in_sizes[0] / 128;          // 50000  (< 65536: u16 src pack)
    const int E = in_sizes[1] / 2;            // 800000
    const int* src = ei;
    const int* dst = ei + E;
    const int HB    = (E + 2047) / 2048;      // hist/scatterA blocks (391)
    const int NBUCK = (N + 255) / 256;        // coarse buckets (196)
    const int GB    = (N + 63) / 64;          // gemm row-tile blocks
    const int NG    = (N + 15) / 16;          // gather blocks (16 nodes/block)

    char* w = (char*)d_ws;
    auto carve = [&](size_t bytes) { char* p = w; w += (bytes + 1023) & ~(size_t)1023; return p; };
    int*    bcount  = (int*)   carve(512 * 4);             // [bcount|bcursor]
    int*    bcursor = bcount + 256;
    uint*   recs    = (uint*)  carve((size_t)E * 4);       // level-A records
    int*    row_ptr = (int*)   carve((size_t)(N + 1) * 4);
    float*  dinv    = (float*) carve((size_t)N * 4);
    ushort* edges   = (ushort*)carve((size_t)E * 2);       // u16 src records
    ushort* h_pre   = (ushort*)carve((size_t)N * 64 * 2);  // bf16 (pre-scaled)
    ushort* h_mid   = (ushort*)carve((size_t)N * 64 * 2);  // bf16 (pre-scaled)

    hipMemsetAsync(bcount, 0, 512 * 4, stream);
    k_hist    <<<HB, 256, 0, stream>>>(dst, bcount, E);
    k_scatterA<<<HB, 256, 0, stream>>>(src, dst, bcount, bcursor, recs, E);
    k_phaseB  <<<NBUCK, 256, 0, stream>>>(recs, bcount, row_ptr, dinv, edges, N, E, NBUCK);
    k_gemm    <<<GB, 256, 0, stream>>>(x, W1, dinv, h_pre, N);
    k_gather1 <<<NG, 256, 0, stream>>>((const uint*)h_pre, row_ptr, edges, dinv,
                                       b1, (uint*)h_mid, N, E);
    k_gather2 <<<NG, 256, 0, stream>>>((const uint*)h_mid, row_ptr, edges, dinv,
                                       Wmu, Wls, bmu, bls, out, N, E);
}

// Round 3
// 182.109 us; speedup vs baseline: 1.8661x; 1.0368x over previous
//
#include <hip/hip_runtime.h>
#include <hip/hip_fp16.h>
#include <math.h>

// ---------------------------------------------------------------------------
// VariationalGCNEncoder: N=50000, E=800000, 128 -> 64 -> {32,32}
// R14: (a) gathers go 8-lane-group (8 nodes/wave, uint4=16B per lane, one
//      128B row per wave-instr). 8-deep unroll = 64 rows in flight per wave
//      (2x R13) -- attacks the latency-bound hypothesis for the ~60-70us
//      gather pair. launch_bounds(256,6) caps VGPR at 85 (no spill with 32
//      VGPR of loads in flight).
//      (b) k_gemm stages W1 (transposed, bf16) in LDS once per block:
//      inner loop's 128 scalar W1 loads/thread -> 16 ds_read_b128.
// Pipeline (7 dispatches):
//   memset(bcount|bcursor) -> hist -> scatterA -> phaseB
//   gemm: hp = dinv[row] * (bf16(x) @ bf16(W1))                     bf16
//   gather1: hm = dinv * relu(dinv*(sum hp[src] + hp[n]) + b1)      bf16
//   gather2: out = dinv*(sum hm[src] + hm[n]) @ [Wmu|Wls] + bias    f32
// ---------------------------------------------------------------------------

typedef unsigned int uint;
typedef unsigned short ushort;
typedef __attribute__((ext_vector_type(8))) short short8;   // 8 bf16 = 4 VGPR
typedef __attribute__((ext_vector_type(4))) float f32x4;    // MFMA acc

__device__ __forceinline__ ushort f2bf(float x) {          // f32 -> bf16 RNE
    uint u = __float_as_uint(x);
    u += 0x7fffu + ((u >> 16) & 1u);
    return (ushort)(u >> 16);
}
__device__ __forceinline__ float bf2f(ushort h) {
    return __uint_as_float((uint)h << 16);
}

// ---- CSR build, level A: coarse histogram (2048 edges/block) ----
__global__ __launch_bounds__(256) void k_hist(
        const int* __restrict__ dst, int* __restrict__ bcount, int E) {
    __shared__ int h[256];
    const int tid = threadIdx.x;
    h[tid] = 0;
    __syncthreads();
    const int base = blockIdx.x * 2048;
    #pragma unroll
    for (int k = 0; k < 8; ++k) {
        int i = base + k * 256 + tid;
        if (i < E) {
            int d = __builtin_nontemporal_load(dst + i);
            atomicAdd(&h[d >> 8], 1);
        }
    }
    __syncthreads();
    if (h[tid]) atomicAdd(&bcount[tid], h[tid]);
}

// ---- level A scatter: rec = src(16) | dstlow(8)<<16 | bucket(8)<<24 ----
__global__ __launch_bounds__(256) void k_scatterA(
        const int* __restrict__ src, const int* __restrict__ dst,
        const int* __restrict__ bcount, int* __restrict__ bcursor,
        uint* __restrict__ recs, int E) {
    __shared__ int h[256];
    __shared__ int p[256];
    __shared__ int rb[256];
    const int tid = threadIdx.x;
    h[tid] = 0;
    __syncthreads();
    const int base = blockIdx.x * 2048;
    uint rec[8]; int rk[8];
    #pragma unroll
    for (int k = 0; k < 8; ++k) {
        int i = base + k * 256 + tid;
        if (i < E) {
            int s = __builtin_nontemporal_load(src + i);
            int d = __builtin_nontemporal_load(dst + i);
            int b = d >> 8;
            rec[k] = (uint)s | ((uint)(d & 255) << 16) | ((uint)b << 24);
            rk[k] = atomicAdd(&h[b], 1);
        }
    }
    int v = bcount[tid];
    p[tid] = v;
    __syncthreads();
    #pragma unroll
    for (int off = 1; off < 256; off <<= 1) {
        int x = (tid >= off) ? p[tid - off] : 0;
        __syncthreads();
        p[tid] += x;
        __syncthreads();
    }
    const int excl = p[tid] - v;
    const int hv = h[tid];
    rb[tid] = excl + (hv ? atomicAdd(&bcursor[tid], hv) : 0);
    __syncthreads();
    #pragma unroll
    for (int k = 0; k < 8; ++k) {
        int i = base + k * 256 + tid;
        if (i < E) recs[rb[rec[k] >> 24] + rk[k]] = rec[k];
    }
}

// ---- level B: one block per bucket; row_ptr+dinv; u16 edge scatter ----
__global__ __launch_bounds__(256, 4) void k_phaseB(
        const uint* __restrict__ recs, const int* __restrict__ bcount,
        int* __restrict__ row_ptr, float* __restrict__ dinv,
        ushort* __restrict__ edges, int N, int E, int NBUCK) {
    __shared__ int h[256];
    __shared__ int p[256];
    __shared__ uint rstage[8192];
    const int tid = threadIdx.x;
    const int bx  = blockIdx.x;
    int v = bcount[tid];
    p[tid] = v;
    h[tid] = 0;
    __syncthreads();
    #pragma unroll
    for (int off = 1; off < 256; off <<= 1) {
        int x = (tid >= off) ? p[tid - off] : 0;
        __syncthreads();
        p[tid] += x;
        __syncthreads();
    }
    const int cnt = bcount[bx];
    const int bs  = p[bx] - cnt;
    const bool stg = (cnt <= 8192);
    for (int i = tid; i < cnt; i += 256) {
        uint r = recs[bs + i];
        if (stg) rstage[i] = r;
        atomicAdd(&h[(r >> 16) & 255], 1);
    }
    __syncthreads();
    v = h[tid];
    p[tid] = v;
    __syncthreads();
    #pragma unroll
    for (int off = 1; off < 256; off <<= 1) {
        int x = (tid >= off) ? p[tid - off] : 0;
        __syncthreads();
        p[tid] += x;
        __syncthreads();
    }
    const int excl = p[tid] - v;
    const int node = bx * 256 + tid;
    if (node < N) {
        row_ptr[node] = bs + excl;
        dinv[node] = rsqrtf((float)(v + 1));
    }
    if (bx == NBUCK - 1 && tid == 0) row_ptr[N] = E;
    h[tid] = excl;
    __syncthreads();
    for (int i = tid; i < cnt; i += 256) {
        uint r = stg ? rstage[i] : recs[bs + i];
        int pos = atomicAdd(&h[(r >> 16) & 255], 1);
        edges[bs + pos] = (ushort)(r & 0xffffu);
    }
}

// ---- MFMA gemm, W1 staged transposed/bf16 in LDS ----
__global__ __launch_bounds__(256, 4) void k_gemm(
        const float* __restrict__ x, const float* __restrict__ W1,
        const float* __restrict__ dinv, ushort* __restrict__ hp, int N) {
    __shared__ ushort Wt[64][136];   // col-major bf16, row stride 272B (16-al)
    const int tid = threadIdx.x;
    #pragma unroll
    for (int it = 0; it < 8; ++it) {           // 8192 elems, 32/thread
        int idx = (it * 256 + tid) * 4;
        int k = idx >> 6, c = idx & 63;
        float4 wv = *(const float4*)(W1 + idx);
        Wt[c + 0][k] = f2bf(wv.x);
        Wt[c + 1][k] = f2bf(wv.y);
        Wt[c + 2][k] = f2bf(wv.z);
        Wt[c + 3][k] = f2bf(wv.w);
    }
    __syncthreads();
    const int w = tid >> 6, l = tid & 63;
    const int m = l & 15, q = l >> 4;
    const int row0 = blockIdx.x * 64 + w * 16;
    const size_t arow = (size_t)min(row0 + m, N - 1);
    f32x4 acc0 = {0.f, 0.f, 0.f, 0.f}, acc1 = acc0, acc2 = acc0, acc3 = acc0;
    #pragma unroll
    for (int kc = 0; kc < 4; ++kc) {
        const int kofs = kc * 32 + q * 8;
        const float4* xr = (const float4*)(x + arow * 128 + kofs);
        float4 xa = xr[0], xb = xr[1];
        short8 a;
        a[0] = (short)f2bf(xa.x); a[1] = (short)f2bf(xa.y);
        a[2] = (short)f2bf(xa.z); a[3] = (short)f2bf(xa.w);
        a[4] = (short)f2bf(xb.x); a[5] = (short)f2bf(xb.y);
        a[6] = (short)f2bf(xb.z); a[7] = (short)f2bf(xb.w);
        short8 b0 = *(const short8*)&Wt[m][kofs];
        short8 b1 = *(const short8*)&Wt[m + 16][kofs];
        short8 b2 = *(const short8*)&Wt[m + 32][kofs];
        short8 b3 = *(const short8*)&Wt[m + 48][kofs];
        acc0 = __builtin_amdgcn_mfma_f32_16x16x32_bf16(a, b0, acc0, 0, 0, 0);
        acc1 = __builtin_amdgcn_mfma_f32_16x16x32_bf16(a, b1, acc1, 0, 0, 0);
        acc2 = __builtin_amdgcn_mfma_f32_16x16x32_bf16(a, b2, acc2, 0, 0, 0);
        acc3 = __builtin_amdgcn_mfma_f32_16x16x32_bf16(a, b3, acc3, 0, 0, 0);
    }
    #pragma unroll
    for (int r = 0; r < 4; ++r) {
        int row = row0 + q * 4 + r;
        if (row >= N) continue;
        float dv = dinv[row];
        ushort* hr = hp + (size_t)row * 64 + m;
        hr[0]  = f2bf(acc0[r] * dv);
        hr[16] = f2bf(acc1[r] * dv);
        hr[32] = f2bf(acc2[r] * dv);
        hr[48] = f2bf(acc3[r] * dv);
    }
}

// ---- 8-lane-group gather: group owns one node; lane owns 8 features ----
// Per 8-edge chunk: one coalesced edges load (2B/lane), then 8 row loads
// (8 lanes x uint4 = 128B each), all independent -> 8 rows in flight per
// group, 64 per wave. No cross-lane reduce (features disjoint across lanes).
__device__ __forceinline__ void gather_grp8(
        const uint* __restrict__ hp, const ushort* __restrict__ edges,
        int beg, int end, int E, int sl, float4& a0, float4& a1) {
    for (int base = beg; base < end; base += 8) {
        const int mrec = (int)edges[min(base + sl, E - 1)];
        const int cnt = end - base;
        if (cnt >= 8) {
            #pragma unroll
            for (int i = 0; i < 8; ++i) {
                const int r = __shfl(mrec, i, 8);
                const uint4 v = *(const uint4*)(hp + (size_t)r * 32 + 4 * sl);
                a0.x += __uint_as_float(v.x << 16);
                a0.y += __uint_as_float(v.x & 0xffff0000u);
                a0.z += __uint_as_float(v.y << 16);
                a0.w += __uint_as_float(v.y & 0xffff0000u);
                a1.x += __uint_as_float(v.z << 16);
                a1.y += __uint_as_float(v.z & 0xffff0000u);
                a1.z += __uint_as_float(v.w << 16);
                a1.w += __uint_as_float(v.w & 0xffff0000u);
            }
        } else {
            #pragma unroll
            for (int i = 0; i < 7; ++i) {     // cnt in 1..7; dups are L1 hits
                const int r = __shfl(mrec, min(i, cnt - 1), 8);
                uint4 v = *(const uint4*)(hp + (size_t)r * 32 + 4 * sl);
                if (i >= cnt) { v.x = 0u; v.y = 0u; v.z = 0u; v.w = 0u; }
                a0.x += __uint_as_float(v.x << 16);
                a0.y += __uint_as_float(v.x & 0xffff0000u);
                a0.z += __uint_as_float(v.y << 16);
                a0.w += __uint_as_float(v.y & 0xffff0000u);
                a1.x += __uint_as_float(v.z << 16);
                a1.y += __uint_as_float(v.z & 0xffff0000u);
                a1.z += __uint_as_float(v.w << 16);
                a1.w += __uint_as_float(v.w & 0xffff0000u);
            }
        }
    }
}

// hm[n] = dinv * relu( dinv * (sum hp[src] + hp[n]) + b1 )   (bf16x2)
__global__ __launch_bounds__(256, 6) void k_gather1(
        const uint* __restrict__ hp, const int* __restrict__ row_ptr,
        const ushort* __restrict__ edges, const float* __restrict__ dinv,
        const float* __restrict__ b1, uint* __restrict__ ho, int N, int E) {
    const int lane = threadIdx.x & 63;
    const int sl = lane & 7;
    const int n = blockIdx.x * 32 + ((threadIdx.x >> 6) << 3) + (lane >> 3);
    const int nc = min(n, N - 1);
    const int beg = row_ptr[nc], end = row_ptr[nc + 1];
    float4 a0 = {0.f, 0.f, 0.f, 0.f}, a1 = a0;
    gather_grp8(hp, edges, beg, end, E, sl, a0, a1);
    const float dv = dinv[nc];
    const uint4 sv = *(const uint4*)(hp + (size_t)nc * 32 + 4 * sl);  // self
    const float4 bA = ((const float4*)b1)[2 * sl];
    const float4 bB = ((const float4*)b1)[2 * sl + 1];
    float s0 = a0.x + bf2f((ushort)sv.x);
    float s1 = a0.y + bf2f((ushort)(sv.x >> 16));
    float s2 = a0.z + bf2f((ushort)sv.y);
    float s3 = a0.w + bf2f((ushort)(sv.y >> 16));
    float s4 = a1.x + bf2f((ushort)sv.z);
    float s5 = a1.y + bf2f((ushort)(sv.z >> 16));
    float s6 = a1.z + bf2f((ushort)sv.w);
    float s7 = a1.w + bf2f((ushort)(sv.w >> 16));
    float h0 = fmaxf(fmaf(dv, s0, bA.x), 0.f) * dv;   // relu then pre-scale
    float h1 = fmaxf(fmaf(dv, s1, bA.y), 0.f) * dv;
    float h2 = fmaxf(fmaf(dv, s2, bA.z), 0.f) * dv;
    float h3 = fmaxf(fmaf(dv, s3, bA.w), 0.f) * dv;
    float h4 = fmaxf(fmaf(dv, s4, bB.x), 0.f) * dv;
    float h5 = fmaxf(fmaf(dv, s5, bB.y), 0.f) * dv;
    float h6 = fmaxf(fmaf(dv, s6, bB.z), 0.f) * dv;
    float h7 = fmaxf(fmaf(dv, s7, bB.w), 0.f) * dv;
    if (n < N) {
        uint4 o;
        o.x = (uint)f2bf(h0) | ((uint)f2bf(h1) << 16);
        o.y = (uint)f2bf(h2) | ((uint)f2bf(h3) << 16);
        o.z = (uint)f2bf(h4) | ((uint)f2bf(h5) << 16);
        o.w = (uint)f2bf(h6) | ((uint)f2bf(h7) << 16);
        *(uint4*)(ho + (size_t)n * 32 + 4 * sl) = o;
    }
}

// g = dinv*(sum hm[src] + hm[n]);  out[n] = g @ [Wmu|Wls] + bias
__global__ __launch_bounds__(256, 6) void k_gather2(
        const uint* __restrict__ hp, const int* __restrict__ row_ptr,
        const ushort* __restrict__ edges, const float* __restrict__ dinv,
        const float* __restrict__ Wmu, const float* __restrict__ Wls,
        const float* __restrict__ bmu, const float* __restrict__ bls,
        float* __restrict__ out, int N, int E) {
    __shared__ __align__(16) float hs[4][8][64];   // [wave][group-node][feat]
    const int lane = threadIdx.x & 63;
    const int sl = lane & 7, grp = lane >> 3;
    const int w = threadIdx.x >> 6;
    const int n = blockIdx.x * 32 + (w << 3) + grp;
    const int nc = min(n, N - 1);
    const int beg = row_ptr[nc], end = row_ptr[nc + 1];
    float4 a0 = {0.f, 0.f, 0.f, 0.f}, a1 = a0;
    gather_grp8(hp, edges, beg, end, E, sl, a0, a1);
    const float dv = dinv[nc];
    const uint4 sv = *(const uint4*)(hp + (size_t)nc * 32 + 4 * sl);
    float4 gA, gB;
    gA.x = dv * (a0.x + bf2f((ushort)sv.x));
    gA.y = dv * (a0.y + bf2f((ushort)(sv.x >> 16)));
    gA.z = dv * (a0.z + bf2f((ushort)sv.y));
    gA.w = dv * (a0.w + bf2f((ushort)(sv.y >> 16)));
    gB.x = dv * (a1.x + bf2f((ushort)sv.z));
    gB.y = dv * (a1.y + bf2f((ushort)(sv.z >> 16)));
    gB.z = dv * (a1.z + bf2f((ushort)sv.w));
    gB.w = dv * (a1.w + bf2f((ushort)(sv.w >> 16)));
    *(float4*)&hs[w][grp][8 * sl]     = gA;        // wave-local LDS: no barrier
    *(float4*)&hs[w][grp][8 * sl + 4] = gB;
    // epilogue: out_row = g @ [Wmu|Wls] + bias for the wave's 8 nodes,
    // two passes of 4 nodes; W column loads hoisted; hs reads broadcast.
    const float* Wsel = (lane < 32) ? (Wmu + lane) : (Wls + (lane - 32));
    const float bias  = (lane < 32) ? bmu[lane] : bls[lane - 32];
    #pragma unroll
    for (int p = 0; p < 2; ++p) {
        float c0 = 0.f, c1 = 0.f, c2 = 0.f, c3 = 0.f;
        #pragma unroll 4
        for (int k = 0; k < 64; ++k) {
            float wv = Wsel[k * 32];
            c0 = fmaf(hs[w][p * 4 + 0][k], wv, c0);
            c1 = fmaf(hs[w][p * 4 + 1][k], wv, c1);
            c2 = fmaf(hs[w][p * 4 + 2][k], wv, c2);
            c3 = fmaf(hs[w][p * 4 + 3][k], wv, c3);
        }
        const int n0 = blockIdx.x * 32 + (w << 3) + p * 4;
        float cs[4] = {c0, c1, c2, c3};
        #pragma unroll
        for (int gg = 0; gg < 4; ++gg) {
            int nn = n0 + gg;
            if (nn >= N) break;
            float t = cs[gg] + bias;
            if (lane < 32) out[(size_t)nn * 32 + lane] = t;
            else           out[(size_t)N * 32 + (size_t)nn * 32 + (lane - 32)] = t;
        }
    }
}

extern "C" void kernel_launch(void* const* d_in, const int* in_sizes, int n_in,
                              void* d_out, int out_size, void* d_ws, size_t ws_size,
                              hipStream_t stream) {
    const float* x   = (const float*)d_in[0];
    const int*   ei  = (const int*)d_in[1];
    const float* W1  = (const float*)d_in[2];
    const float* b1  = (const float*)d_in[3];
    const float* Wmu = (const float*)d_in[4];
    const float* bmu = (const float*)d_in[5];
    const float* Wls = (const float*)d_in[6];
    const float* bls = (const float*)d_in[7];
    float* out = (float*)d_out;

    const int N = in_sizes[0] / 128;          // 50000  (< 65536: u16 src pack)
    const int E = in_sizes[1] / 2;            // 800000
    const int* src = ei;
    const int* dst = ei + E;
    const int HB    = (E + 2047) / 2048;      // hist/scatterA blocks (391)
    const int NBUCK = (N + 255) / 256;        // coarse buckets (196)
    const int GB    = (N + 63) / 64;          // gemm row-tile blocks
    const int NG    = (N + 31) / 32;          // gather blocks (32 nodes/block)

    char* w = (char*)d_ws;
    auto carve = [&](size_t bytes) { char* p = w; w += (bytes + 1023) & ~(size_t)1023; return p; };
    int*    bcount  = (int*)   carve(512 * 4);             // [bcount|bcursor]
    int*    bcursor = bcount + 256;
    uint*   recs    = (uint*)  carve((size_t)E * 4);       // level-A records
    int*    row_ptr = (int*)   carve((size_t)(N + 1) * 4);
    float*  dinv    = (float*) carve((size_t)N * 4);
    ushort* edges   = (ushort*)carve((size_t)E * 2);       // u16 src records
    ushort* h_pre   = (ushort*)carve((size_t)N * 64 * 2);  // bf16 (pre-scaled)
    ushort* h_mid   = (ushort*)carve((size_t)N * 64 * 2);  // bf16 (pre-scaled)

    hipMemsetAsync(bcount, 0, 512 * 4, stream);
    k_hist    <<<HB, 256, 0, stream>>>(dst, bcount, E);
    k_scatterA<<<HB, 256, 0, stream>>>(src, dst, bcount, bcursor, recs, E);
    k_phaseB  <<<NBUCK, 256, 0, stream>>>(recs, bcount, row_ptr, dinv, edges, N, E, NBUCK);
    k_gemm    <<<GB, 256, 0, stream>>>(x, W1, dinv, h_pre, N);
    k_gather1 <<<NG, 256, 0, stream>>>((const uint*)h_pre, row_ptr, edges, dinv,
                                       b1, (uint*)h_mid, N, E);
    k_gather2 <<<NG, 256, 0, stream>>>((const uint*)h_mid, row_ptr, edges, dinv,
                                       Wmu, Wls, bmu, bls, out, N, E);
}